// Round 13
// baseline (54.137 us; speedup 1.0000x reference)
//
#include <hip/hip_runtime.h>
#include <hip/hip_cooperative_groups.h>

namespace cg = cooperative_groups;

// MetaSR scale-4 as a single cooperative kernel.
// Exact-in-fp32: iy=y>>2, rel0=(y&3)*0.25, rel1=(x&3)*0.25, r_rev=0.25
// -> 16 distinct MLP inputs -> W[48][576] (bf16, K reordered k=tap*64+c).
// Phase A: each of 256 blocks computes 108 of the 27648 W entries
//   (block = (s, chunk); h[256] once per block; 2-thread K-split dots).
// grid.sync()  (device-scope fences: predw16 visible across XCDs)
// Phase B: MFMA GEMM out[48][4096] = W @ unfold(feat), B-fragments built
//   in registers from L2 (8 ch-stride loads + pack per kk), no LDS/barriers.
// R5 vs R12 identical 16.5us totals with disjoint kernels => launch gaps
// dominate; this removes them.

#define NOUT 1728

typedef short bf16x8 __attribute__((ext_vector_type(8)));
typedef float f32x4  __attribute__((ext_vector_type(4)));

__device__ inline unsigned short bf16r(float a) {
    const unsigned ua = __builtin_bit_cast(unsigned, a);
    return (unsigned short)((ua + 0x7FFFu + ((ua >> 16) & 1u)) >> 16);
}
__device__ inline unsigned bf16pack(float a, float b) {
    unsigned ua = __builtin_bit_cast(unsigned, a);
    unsigned ub = __builtin_bit_cast(unsigned, b);
    ua = (ua + 0x7FFFu + ((ua >> 16) & 1u)) >> 16;
    ub = (ub + 0x7FFFu + ((ub >> 16) & 1u)) >> 16;
    return ua | (ub << 16);
}

__global__ __launch_bounds__(256) void k_fused(
    const float* __restrict__ feat, const float* __restrict__ w1,
    const float* __restrict__ b1,   const float* __restrict__ w2,
    const float* __restrict__ b2,   unsigned short* __restrict__ predw16,
    float* __restrict__ out)
{
    __shared__ float h[256];
    __shared__ float hred[216];

    const int tid = threadIdx.x;
    const int bid = blockIdx.x;

    // ---------------- Phase A: predw16[m=48][k=tap*64+c] -------------------
    {
        const int s     = bid >> 4;        // subpixel 0..15
        const int chunk = bid & 15;        // 16 chunks of 108 outputs

        const float rel0 = (float)(s >> 2) * 0.25f;
        const float rel1 = (float)(s & 3) * 0.25f;

        float pre = fmaf(w1[tid], rel0,
                    fmaf(w1[256 + tid], rel1,
                    fmaf(w1[512 + tid], 0.25f, b1[tid])));
        h[tid] = fmaxf(pre, 0.0f);
        __syncthreads();

        if (tid < 216) {
            const int t  = tid >> 1;
            const int kh = tid & 1;
            const int o  = chunk * 108 + t;            // 0..1727
            const float* w2c = w2 + kh * 128 * NOUT + o;
            const float* hq  = h + kh * 128;
            float acc = 0.0f;
            #pragma unroll 8
            for (int j = 0; j < 128; ++j)
                acc = fmaf(hq[j], w2c[j * NOUT], acc);
            hred[tid] = acc;
        }
        __syncthreads();

        if (tid < 108) {
            const int o = chunk * 108 + tid;           // o = ct*3 + k
            const float a = hred[2 * tid] + hred[2 * tid + 1] + b2[o];
            const int ct = o / 3;
            const int k  = o - ct * 3;
            const int c  = (ct * 7282) >> 16;          // ct/9 exact, ct<576
            const int tp = ct - c * 9;
            const int m  = s * 3 + k;
            predw16[m * 576 + tp * 64 + c] = bf16r(a);
        }
    }

    cg::this_grid().sync();

    // ---------------- Phase B: MFMA conv -----------------------------------
    if (tid < 192) {
        const int lane = tid & 63;
        const int mt   = tid >> 6;          // m-tile 0..2
        const int n    = bid;               // n-tile 0..255
        const int y0   = n >> 2;
        const int x0   = (n & 3) << 4;

        const int lc = lane & 15;           // B col (cell) / A row (m)
        const int lk = lane >> 4;           // k subgroup 0..3

        int xadr[3]; float xmsk[3];
        #pragma unroll
        for (int d = 0; d < 3; ++d) {
            const int rx = x0 + lc + d - 1;
            xmsk[d] = ((unsigned)rx < 64u) ? 1.0f : 0.0f;
            xadr[d] = rx < 0 ? 0 : (rx > 63 ? 63 : rx);
        }
        int yadr[3]; float ymsk[3];
        #pragma unroll
        for (int d = 0; d < 3; ++d) {
            const int ry = y0 + d - 1;
            ymsk[d] = ((unsigned)ry < 64u) ? 1.0f : 0.0f;
            yadr[d] = (ry < 0 ? 0 : (ry > 63 ? 63 : ry)) << 6;
        }

        const unsigned short* arow = predw16 + (mt * 16 + lc) * 576 + (lk << 3);

        f32x4 acc = {0.0f, 0.0f, 0.0f, 0.0f};

        #pragma unroll 2
        for (int kk = 0; kk < 18; ++kk) {
            const int tap = kk >> 1;
            const int dr  = (tap >= 6) ? 2 : (tap >= 3 ? 1 : 0);
            const int dc  = tap - dr * 3;
            const int c0  = ((kk & 1) << 5) + (lk << 3);
            const float* fb = feat + (c0 << 12) + yadr[dr] + xadr[dc];
            const float  mk = ymsk[dr] * xmsk[dc];

            const float v0 = fb[0]       * mk;
            const float v1 = fb[1 << 12] * mk;
            const float v2 = fb[2 << 12] * mk;
            const float v3 = fb[3 << 12] * mk;
            const float v4 = fb[4 << 12] * mk;
            const float v5 = fb[5 << 12] * mk;
            const float v6 = fb[6 << 12] * mk;
            const float v7 = fb[7 << 12] * mk;

            uint4 bb;
            bb.x = bf16pack(v0, v1);
            bb.y = bf16pack(v2, v3);
            bb.z = bf16pack(v4, v5);
            bb.w = bf16pack(v6, v7);
            const bf16x8 bfrag = __builtin_bit_cast(bf16x8, bb);

            const bf16x8 afrag = *(const bf16x8*)(arow + 32 * kk);

            acc = __builtin_amdgcn_mfma_f32_16x16x32_bf16(afrag, bfrag, acc,
                                                          0, 0, 0);
        }

        // D: col = lane&15 (cell), row = lk*4 + r (within m-tile)
        #pragma unroll
        for (int r = 0; r < 4; ++r) {
            const int m = mt * 16 + (lk << 2) + r;
            const int s = (m * 171) >> 9;   // m/3 exact for m<48
            const int k = m - s * 3;
            const int y = (y0 << 2) + (s >> 2);
            const int x = ((x0 + lc) << 2) + (s & 3);
            out[k * 65536 + y * 256 + x] = acc[r];
        }
    }
}

extern "C" void kernel_launch(void* const* d_in, const int* in_sizes, int n_in,
                              void* d_out, int out_size, void* d_ws, size_t ws_size,
                              hipStream_t stream) {
    const float* feat = (const float*)d_in[0];
    const float* w1   = (const float*)d_in[1];
    const float* b1   = (const float*)d_in[2];
    const float* w2   = (const float*)d_in[3];
    const float* b2   = (const float*)d_in[4];
    float* out = (float*)d_out;
    unsigned short* predw16 = (unsigned short*)d_ws;  // 48*576*2 = 55296 B

    void* args[] = {(void*)&feat, (void*)&w1, (void*)&b1, (void*)&w2,
                    (void*)&b2, (void*)&predw16, (void*)&out};
    hipLaunchCooperativeKernel(reinterpret_cast<void*>(k_fused),
                               dim3(256), dim3(256), args, 0, stream);
}

// Round 14
// 14.425 us; speedup vs baseline: 3.7529x; 3.7529x over previous
//
#include <hip/hip_runtime.h>

// MetaSR scale-4 as MFMA GEMM: out[48][4096] = W[48][576] @ U[576][4096].
// 16 distinct MLP inputs (exact in fp32) -> W rows m = s*3+k, K reordered
// k = tap*64 + c so B-fragments build in registers from L2/HBM.
// R13: replays run HBM-cold (harness poison fills flush L2+L3), so the conv
// is cold-load-latency-bound. Fix = concurrency: K-split the 18 kk-steps
// over 4 waves/block (kk mod 4), grid 768 = 3mt x 256nt -> 12 waves/CU
// (was 3), fp32 LDS reduce, wave0 writes. Launch gaps measured <1us (R2),
// so 2 launches stay.

#define NOUT 1728

typedef short bf16x8 __attribute__((ext_vector_type(8)));
typedef float f32x4  __attribute__((ext_vector_type(4)));

__device__ inline unsigned short bf16r(float a) {
    const unsigned ua = __builtin_bit_cast(unsigned, a);
    return (unsigned short)((ua + 0x7FFFu + ((ua >> 16) & 1u)) >> 16);
}
__device__ inline unsigned bf16pack(float a, float b) {
    unsigned ua = __builtin_bit_cast(unsigned, a);
    unsigned ub = __builtin_bit_cast(unsigned, b);
    ua = (ua + 0x7FFFu + ((ua >> 16) & 1u)) >> 16;
    ub = (ub + 0x7FFFu + ((ub >> 16) & 1u)) >> 16;
    return ua | (ub << 16);
}

// ---------------- Kernel 1: W as bf16, layout [m=48][k=tap*64+c] -----------
// grid 432 = 16 s * 27 chunks of 64 outputs; block 256 = 64 outputs * 4 Ksplit
__global__ __launch_bounds__(256) void k_predw(
    const float* __restrict__ w1, const float* __restrict__ b1,
    const float* __restrict__ w2, const float* __restrict__ b2,
    unsigned short* __restrict__ predw16)
{
    __shared__ float h[256];
    __shared__ float red[256];
    const int tid   = threadIdx.x;
    const int s     = blockIdx.x / 27;
    const int chunk = blockIdx.x - s * 27;

    const float rel0 = (float)(s >> 2) * 0.25f;
    const float rel1 = (float)(s & 3) * 0.25f;

    float pre = fmaf(w1[tid], rel0,
                fmaf(w1[256 + tid], rel1,
                fmaf(w1[512 + tid], 0.25f, b1[tid])));
    h[tid] = fmaxf(pre, 0.0f);
    __syncthreads();

    const int olocal = tid & 63;
    const int q      = tid >> 6;           // K-quarter
    const int o      = chunk * 64 + olocal;
    const float* w2c = w2 + q * 64 * NOUT + o;
    const float* hq  = h + q * 64;

    float acc = 0.0f;
    #pragma unroll 16
    for (int j = 0; j < 64; ++j)
        acc = fmaf(hq[j], w2c[j * NOUT], acc);
    red[tid] = acc;
    __syncthreads();

    if (tid < 64) {
        const int oo = chunk * 64 + tid;   // oo = ct*3 + k
        float a = red[tid] + red[tid + 64] + red[tid + 128] + red[tid + 192]
                + b2[oo];
        const int ct = oo / 3;
        const int k  = oo - ct * 3;
        const int c  = (ct * 7282) >> 16;  // ct/9 exact for ct<576
        const int tp = ct - c * 9;
        const int m  = s * 3 + k;
        predw16[m * 576 + tp * 64 + c] = bf16r(a);
    }
}

// ---------------- Kernel 2: MFMA conv, 4-wave K-split ----------------------
// grid 768: mt = bid>>8, nt = bid&255 (y0 = nt>>2, x0 = (nt&3)*16)
// block 256 = 4 waves; wave w handles kk in {w, w+4, ...} of 18 k-steps
__global__ __launch_bounds__(256) void k_conv(
    const float* __restrict__ feat, const unsigned short* __restrict__ predw16,
    float* __restrict__ out)
{
    __shared__ f32x4 red[3 * 64];          // partials of waves 1..3

    const int tid  = threadIdx.x;
    const int lane = tid & 63;
    const int w    = tid >> 6;            // K-split wave 0..3
    const int bid  = blockIdx.x;
    const int mt   = bid >> 8;            // m-tile 0..2
    const int nt   = bid & 255;           // n-tile 0..255
    const int y0   = nt >> 2;
    const int x0   = (nt & 3) << 4;

    const int lc = lane & 15;             // B col (cell) / A row (m)
    const int lk = lane >> 4;             // k subgroup 0..3

    // per-lane clamped addr + masks for dc,dr in {0,1,2} (offset -1)
    int xadr[3]; float xmsk[3];
    #pragma unroll
    for (int d = 0; d < 3; ++d) {
        const int rx = x0 + lc + d - 1;
        xmsk[d] = ((unsigned)rx < 64u) ? 1.0f : 0.0f;
        xadr[d] = rx < 0 ? 0 : (rx > 63 ? 63 : rx);
    }
    int yadr[3]; float ymsk[3];
    #pragma unroll
    for (int d = 0; d < 3; ++d) {
        const int ry = y0 + d - 1;
        ymsk[d] = ((unsigned)ry < 64u) ? 1.0f : 0.0f;
        yadr[d] = (ry < 0 ? 0 : (ry > 63 ? 63 : ry)) << 6;
    }

    const unsigned short* arow = predw16 + (mt * 16 + lc) * 576 + (lk << 3);

    f32x4 acc = {0.0f, 0.0f, 0.0f, 0.0f};

    #pragma unroll
    for (int i = 0; i < 5; ++i) {
        const int kk = w + (i << 2);
        if (kk < 18) {                    // wave-uniform predicate
            const int tap = kk >> 1;
            const int dr  = (tap >= 6) ? 2 : (tap >= 3 ? 1 : 0);
            const int dc  = tap - dr * 3;
            const int c0  = ((kk & 1) << 5) + (lk << 3);
            const float* fb = feat + (c0 << 12) + yadr[dr] + xadr[dc];
            const float  mk = ymsk[dr] * xmsk[dc];

            const float v0 = fb[0]       * mk;
            const float v1 = fb[1 << 12] * mk;
            const float v2 = fb[2 << 12] * mk;
            const float v3 = fb[3 << 12] * mk;
            const float v4 = fb[4 << 12] * mk;
            const float v5 = fb[5 << 12] * mk;
            const float v6 = fb[6 << 12] * mk;
            const float v7 = fb[7 << 12] * mk;

            uint4 bb;
            bb.x = bf16pack(v0, v1);
            bb.y = bf16pack(v2, v3);
            bb.z = bf16pack(v4, v5);
            bb.w = bf16pack(v6, v7);
            const bf16x8 bfrag = __builtin_bit_cast(bf16x8, bb);
            const bf16x8 afrag = *(const bf16x8*)(arow + 32 * kk);

            acc = __builtin_amdgcn_mfma_f32_16x16x32_bf16(afrag, bfrag, acc,
                                                          0, 0, 0);
        }
    }

    // 4-wave fp32 reduce (fixed order -> deterministic)
    if (w > 0) red[(w - 1) * 64 + lane] = acc;
    __syncthreads();

    if (w == 0) {
        #pragma unroll
        for (int q = 0; q < 3; ++q) {
            const f32x4 v = red[q * 64 + lane];
            acc[0] += v[0]; acc[1] += v[1]; acc[2] += v[2]; acc[3] += v[3];
        }
        // D: col = lane&15 (cell), row = lk*4 + r (within m-tile)
        #pragma unroll
        for (int r = 0; r < 4; ++r) {
            const int m = mt * 16 + (lk << 2) + r;
            const int s = (m * 171) >> 9;  // m/3 exact for m<48
            const int k = m - s * 3;
            const int y = (y0 << 2) + (s >> 2);
            const int x = ((x0 + lc) << 2) + (s & 3);
            out[k * 65536 + y * 256 + x] = acc[r];
        }
    }
}

extern "C" void kernel_launch(void* const* d_in, const int* in_sizes, int n_in,
                              void* d_out, int out_size, void* d_ws, size_t ws_size,
                              hipStream_t stream) {
    const float* feat = (const float*)d_in[0];
    const float* w1   = (const float*)d_in[1];
    const float* b1   = (const float*)d_in[2];
    const float* w2   = (const float*)d_in[3];
    const float* b2   = (const float*)d_in[4];
    float* out = (float*)d_out;
    unsigned short* predw16 = (unsigned short*)d_ws;  // 48*576*2 = 55296 B

    hipLaunchKernelGGL(k_predw, dim3(432), dim3(256), 0, stream,
                       w1, b1, w2, b2, predw16);
    hipLaunchKernelGGL(k_conv, dim3(768), dim3(256), 0, stream,
                       feat, predw16, out);
}